// Round 13
// baseline (374.371 us; speedup 1.0000x reference)
//
#include <hip/hip_runtime.h>

typedef __attribute__((ext_vector_type(8))) short s8;
typedef __attribute__((ext_vector_type(4))) float f4;

#define PREDq 192

__device__ inline short f2bf(float f) {
    union { float f; unsigned u; } v; v.f = f;
    unsigned r = (v.u + 0x7FFF + ((v.u >> 16) & 1)) >> 16;
    return (short)r;
}
__device__ inline float bf2f(short h) {
    union { unsigned u; float f; } v;
    v.u = ((unsigned)(unsigned short)h) << 16;
    return v.f;
}

// ---------------- fused setup: twiddles + weight transposes + ow->bf16 + stats + embed ----------------
__global__ void k_prep(const float* __restrict__ xw, const float* __restrict__ dw,
                       const float* __restrict__ Kr, const float* __restrict__ Ki,
                       const float* __restrict__ ow, const float* __restrict__ x,
                       short* __restrict__ twA,
                       float* __restrict__ xwT, float* __restrict__ dwT,
                       float* __restrict__ ktr, float* __restrict__ kti,
                       short* __restrict__ owh,
                       float* __restrict__ means, float* __restrict__ stdev,
                       float* __restrict__ enc) {
    if (blockIdx.x >= 3072) {           // ---- stats + embed blocks ----
        int bc = blockIdx.x - 3072;
        int b = bc >> 5, c = bc & 31;
        int t = threadIdx.x;
        __shared__ float xrow[512];
        __shared__ float r1[4], r2[4];
        float s1 = 0.f, s2 = 0.f;
        for (int tt = t; tt < 512; tt += 256) {
            float v = x[(b * 512 + tt) * 32 + c];
            xrow[tt] = v;
            s1 += v; s2 += v * v;
        }
        #pragma unroll
        for (int off = 32; off > 0; off >>= 1) {
            s1 += __shfl_xor(s1, off);
            s2 += __shfl_xor(s2, off);
        }
        int wave = t >> 6, lane = t & 63;
        if (lane == 0) { r1[wave] = s1; r2[wave] = s2; }
        __syncthreads();
        float S1 = r1[0] + r1[1] + r1[2] + r1[3];
        float S2 = r2[0] + r2[1] + r2[2] + r2[3];
        float mu = S1 * (1.f / 512.f);
        float var = S2 * (1.f / 512.f) - mu * mu;
        float sd = sqrtf(var + 1e-5f);
        float inv = 1.f / sd;
        if (t == 0) { means[bc] = mu; stdev[bc] = sd; }
        #pragma unroll
        for (int k = 0; k < 16; k++) {
            int idx = k * 256 + t;                 // < 4096
            int p = idx >> 7, dd = idx & 127;
            int m = dd >> 4, l = dd & 15;
            int tt2 = p * 16 + l;
            float v = 0.f;
            if (tt2 >= 7) v = (xrow[tt2 - 7 + m] - mu) * inv;
            enc[bc * 4096 + idx] = v;              // coalesced
        }
        return;
    }
    int idx = blockIdx.x * 256 + threadIdx.x;
    if (idx < 8192) {                   // twA bf16 [(x*2+c)][d]: c==0 cos, c==1 -sin
        int n = idx >> 7, d = idx & 127;
        int xx = n >> 1, c = n & 1;
        float ang = (float)((xx * d) & 127) * 0.04908738521234052f; // 2*pi/128
        twA[idx] = f2bf((c == 0) ? cosf(ang) : -sinf(ang));
    }
    if (idx < 2 * 128 * 80) {           // xwT[li][d][80]
        int li = idx / 10240, rem = idx % 10240, d = rem / 80, t = rem % 80;
        xwT[idx] = (t < 72) ? xw[li * 9216 + t * 128 + d] : 0.f;
    }
    if (idx < 2 * 8 * 128) {            // dwT[li][r][128]
        int li = idx / 1024, rem = idx % 1024, r = rem / 128, d = rem % 128;
        dwT[idx] = dw[li * 1024 + d * 8 + r];
    }
    if (idx < 2 * 32 * 32 * 32) {       // ktr/kti [li][x][o][i]
        int li = idx >> 15, rem = idx & 32767;
        int xx = rem >> 10, o = (rem >> 5) & 31, i = rem & 31;
        int src = ((li * 32 + i) * 32 + o) * 32 + xx;
        ktr[idx] = Kr[src];
        kti[idx] = Ki[src];
    }
    if (idx < 192 * 4096) {             // owh bf16, native [t][k]
        owh[idx] = f2bf(ow[idx]);
    }
}

// ---------------- LayerNorm + projections ----------------
__global__ __launch_bounds__(128) void k_lnproj(const float* __restrict__ enc,
                         const float* __restrict__ xwT,  // [d][80]
                         const float* __restrict__ dwT,  // [r][128]
                         const float* __restrict__ db,   // (128)
                         const float* __restrict__ g, const float* __restrict__ bb,
                         float* __restrict__ xnR,        // [rp][d]
                         float* __restrict__ deltaT,     // [rp][d]
                         float* __restrict__ BmR,        // [rp][s]
                         float* __restrict__ CmT) {      // [o][rp]
    int r = blockIdx.x;          // bc*32+p
    int bc = r >> 5, p = r & 31;
    int rp = p * 256 + bc;
    int t = threadIdx.x;         // 128
    __shared__ float xs[128];
    __shared__ float red[4];
    __shared__ float dr[8];
    float e = enc[r * 128 + t];
    float s1 = e, s2 = e * e;
    #pragma unroll
    for (int off = 32; off > 0; off >>= 1) {
        s1 += __shfl_xor(s1, off);
        s2 += __shfl_xor(s2, off);
    }
    if ((t & 63) == 0) { red[(t >> 6) * 2] = s1; red[(t >> 6) * 2 + 1] = s2; }
    __syncthreads();
    float mu = (red[0] + red[2]) * (1.f / 128.f);
    float var = (red[1] + red[3]) * (1.f / 128.f) - mu * mu;
    float inv = rsqrtf(var + 1e-5f);
    float v = (e - mu) * inv * g[t] + bb[t];
    xs[t] = v;
    xnR[rp * 128 + t] = v;
    __syncthreads();
    if (t < 80) {
        float acc = 0.f;
        const f4* xs4 = (const f4*)xs;
        #pragma unroll 8
        for (int dq = 0; dq < 32; dq++) {
            f4 xv = xs4[dq];
            const float* wp = xwT + dq * 320 + t;
            acc += xv[0] * wp[0] + xv[1] * wp[80] + xv[2] * wp[160] + xv[3] * wp[240];
        }
        if (t < 8) dr[t] = acc;
        else if (t < 40) BmR[rp * 32 + (t - 8)] = acc;
        else if (t < 72) CmT[(t - 40) * 8192 + rp] = acc;
    }
    __syncthreads();
    float a = db[t];
    #pragma unroll
    for (int rr = 0; rr < 8; rr++) a += dr[rr] * dwT[rr * 128 + t];
    float sp = fmaxf(a, 0.f) + log1pf(expf(-fabsf(a)));
    deltaT[rp * 128 + t] = sp;
}

// ---------------- scan carry: exact fp32 scan over p=0..15, checkpoint h15 ----------------
__global__ __launch_bounds__(128) void k_carry(const float* __restrict__ deltaT,  // [rp][d]
                                               const float* __restrict__ xnR,     // [rp][d]
                                               const float* __restrict__ BmR,     // [rp][s]
                                               const float* __restrict__ Alog,
                                               float* __restrict__ carry) {       // [bc][s][d] fp32
    int bc = blockIdx.x >> 5;
    int s  = blockIdx.x & 31;
    int d  = threadIdx.x;
    float A = -__expf(Alog[d * 32 + s]);
    const float* dptr = deltaT + bc * 128 + d;
    const float* xptr = xnR + bc * 128 + d;
    int bvbase = bc * 32 + s;
    float h = 0.f;
    float dl = dptr[0], xv = xptr[0], bv = BmR[bvbase];
    #pragma unroll 4
    for (int p = 0; p < 16; p++) {
        float dln = 0.f, xvn = 0.f, bvn = 0.f;
        if (p < 15) {
            dln = dptr[(p + 1) * 32768];
            xvn = xptr[(p + 1) * 32768];
            bvn = BmR[(p + 1) * 8192 + bvbase];
        }
        h = __expf(dl * A) * h + dl * xv * bv;
        dl = dln; xv = xvn; bv = bvn;
    }
    carry[(bc * 32 + s) * 128 + d] = h;
}

// ---------------- fused scan + MFMA DFT, wave-autonomous, p-halved via carry ----------------
// 1 wave per (bc, s-half, p-half). lane=(q,l15) holds h for d = kt*32+q*8+j at s=s0+l15
// (MFMA B-fragment layout). ph=1 waves resume from fp32 carry (bit-exact).
// xfh layout: [m=(x*2+c)][rp][s]; xfh stores are NON-TEMPORAL (protect L2 for deltaT/xnR).
__global__ __launch_bounds__(64) void k_scandft(const float* __restrict__ deltaT,  // [rp][d]
                                                const float* __restrict__ xnR,     // [rp][d]
                                                const float* __restrict__ BmR,     // [rp][s]
                                                const float* __restrict__ Alog,
                                                const short* __restrict__ twA,
                                                const float* __restrict__ carry,   // [bc][s][d]
                                                short* __restrict__ xfh) {
    int bc = blockIdx.x >> 2;
    int s0 = ((blockIdx.x >> 1) & 1) * 16;
    int ph = blockIdx.x & 1;
    int p0 = ph * 16;
    int lane = threadIdx.x;
    int l15 = lane & 15, q = lane >> 4;
    int s = s0 + l15;

    __shared__ float dlb[2][128];
    __shared__ float xvb[2][128];

    // twiddle A-fragments: 4 m-tiles x 4 kt (one-time)
    s8 afr[4][4];
    #pragma unroll
    for (int mt = 0; mt < 4; mt++)
        #pragma unroll
        for (int kt = 0; kt < 4; kt++)
            afr[mt][kt] = *(const s8*)(twA + (mt * 16 + l15) * 128 + kt * 32 + q * 8);

    // scan decay per state (one-time scattered loads)
    float A[4][8], h[4][8];
    #pragma unroll
    for (int kt = 0; kt < 4; kt++)
        #pragma unroll
        for (int j = 0; j < 8; j++) {
            int d = kt * 32 + q * 8 + j;
            A[kt][j] = -__expf(Alog[d * 32 + s]);
        }
    if (ph) {      // resume from checkpoint (quad-broadcast f4 loads, once)
        const f4* cb = (const f4*)(carry + (bc * 32 + s) * 128);
        #pragma unroll
        for (int kt = 0; kt < 4; kt++) {
            f4 c0 = cb[kt * 8 + q * 2];
            f4 c1 = cb[kt * 8 + q * 2 + 1];
            #pragma unroll
            for (int j = 0; j < 4; j++) { h[kt][j] = c0[j]; h[kt][4 + j] = c1[j]; }
        }
    } else {
        #pragma unroll
        for (int kt = 0; kt < 4; kt++)
            #pragma unroll
            for (int j = 0; j < 8; j++) h[kt][j] = 0.f;
    }

    const float2* dp2 = (const float2*)deltaT;
    const float2* xp2 = (const float2*)xnR;
    int rbase = bc * 64 + lane;            // float2 index of row element
    int bvbase = bc * 32 + s;

    // stage p = p0
    {
        float2 dv = dp2[p0 * 16384 + rbase];
        float2 xv = xp2[p0 * 16384 + rbase];
        ((float2*)&dlb[0][0])[lane] = dv;
        ((float2*)&xvb[0][0])[lane] = xv;
    }
    float bvc = BmR[p0 * 8192 + bvbase];

    for (int pi = 0; pi < 16; pi++) {
        int p = p0 + pi;
        int buf = pi & 1;
        // prefetch next p (global)
        float2 dnxt, xnxt; float bvn = 0.f;
        if (pi < 15) {
            dnxt = dp2[(p + 1) * 16384 + rbase];
            xnxt = xp2[(p + 1) * 16384 + rbase];
            bvn  = BmR[(p + 1) * 8192 + bvbase];
        }
        // scan update + pack B fragments from registers
        s8 bfr[4];
        #pragma unroll
        for (int kt = 0; kt < 4; kt++) {
            f4 dl0 = *(const f4*)(&dlb[buf][kt * 32 + q * 8]);      // quad-broadcast b128
            f4 dl1 = *(const f4*)(&dlb[buf][kt * 32 + q * 8 + 4]);
            f4 xv0 = *(const f4*)(&xvb[buf][kt * 32 + q * 8]);
            f4 xv1 = *(const f4*)(&xvb[buf][kt * 32 + q * 8 + 4]);
            #pragma unroll
            for (int j = 0; j < 4; j++) {
                float dl = dl0[j], xv = xv0[j];
                h[kt][j] = __expf(dl * A[kt][j]) * h[kt][j] + dl * xv * bvc;
            }
            #pragma unroll
            for (int j = 0; j < 4; j++) {
                float dl = dl1[j], xv = xv1[j];
                h[kt][4 + j] = __expf(dl * A[kt][4 + j]) * h[kt][4 + j] + dl * xv * bvc;
            }
            union { int i[4]; s8 v; } u;
            #pragma unroll
            for (int t2 = 0; t2 < 4; t2++) {
                int lo = __float_as_int(h[kt][2 * t2]);
                int hi = __float_as_int(h[kt][2 * t2 + 1]);
                u.i[t2] = __builtin_amdgcn_perm(hi, lo, 0x07060302);  // [hi.hi16 | lo.hi16]
            }
            bfr[kt] = u.v;
        }
        // stage next p into alternate LDS buffer (wave-local, no barrier)
        if (pi < 15) {
            ((float2*)&dlb[buf ^ 1][0])[lane] = dnxt;
            ((float2*)&xvb[buf ^ 1][0])[lane] = xnxt;
            bvc = bvn;
        }
        // MFMA: 4 m-tiles of 16 modes
        f4 acc0 = {0.f, 0.f, 0.f, 0.f}, acc1 = acc0, acc2 = acc0, acc3 = acc0;
        #pragma unroll
        for (int kt = 0; kt < 4; kt++) {
            acc0 = __builtin_amdgcn_mfma_f32_16x16x32_bf16(afr[0][kt], bfr[kt], acc0, 0, 0, 0);
            acc1 = __builtin_amdgcn_mfma_f32_16x16x32_bf16(afr[1][kt], bfr[kt], acc1, 0, 0, 0);
            acc2 = __builtin_amdgcn_mfma_f32_16x16x32_bf16(afr[2][kt], bfr[kt], acc2, 0, 0, 0);
            acc3 = __builtin_amdgcn_mfma_f32_16x16x32_bf16(afr[3][kt], bfr[kt], acc3, 0, 0, 0);
        }
        // D[row=q*4+r][col=l15] -> m = mt*16 + q*4 + r  (non-temporal stores)
        int rp = p * 256 + bc;
        long ob = (long)rp * 32 + s;
        #pragma unroll
        for (int r = 0; r < 4; r++) {
            int m = q * 4 + r;
            __builtin_nontemporal_store((short)(__float_as_int(acc0[r]) >> 16), &xfh[(m +  0) * 262144 + ob]);
            __builtin_nontemporal_store((short)(__float_as_int(acc1[r]) >> 16), &xfh[(m + 16) * 262144 + ob]);
            __builtin_nontemporal_store((short)(__float_as_int(acc2[r]) >> 16), &xfh[(m + 32) * 262144 + ob]);
            __builtin_nontemporal_store((short)(__float_as_int(acc3[r]) >> 16), &xfh[(m + 48) * 262144 + ob]);
        }
    }
}

// ---------------- mode mixing: u = K·Cm (SGPR weights), g = <xf, u> ----------------
__global__ __launch_bounds__(256) void k_mix(const short* __restrict__ xfh,  // [m][rp][s]
                                             const float* __restrict__ CmT,  // [o][rp]
                                             const float* __restrict__ ktr,  // [x][o][i]
                                             const float* __restrict__ kti,
                                             float* __restrict__ gbuf) {     // [x2c][rp]
    int x = blockIdx.x >> 5;
    int rp = (blockIdx.x & 31) * 256 + threadIdx.x;
    const float* kr = ktr + x * 1024;   // wave-uniform -> s_load bursts
    const float* ki = kti + x * 1024;
    float ur[32], ui[32];
    #pragma unroll
    for (int i = 0; i < 32; i++) { ur[i] = 0.f; ui[i] = 0.f; }
    for (int o = 0; o < 32; o++) {
        float co = CmT[o * 8192 + rp];
        const float* kro = kr + o * 32;
        const float* kio = ki + o * 32;
        #pragma unroll
        for (int i = 0; i < 32; i++) {
            ur[i] = fmaf(co, kro[i], ur[i]);
            ui[i] = fmaf(co, kio[i], ui[i]);
        }
    }
    const s8* pr = (const s8*)(xfh + (x * 2 + 0) * 262144 + rp * 32);  // 64B/lane contiguous
    const s8* pi = (const s8*)(xfh + (x * 2 + 1) * 262144 + rp * 32);
    s8 vr0 = __builtin_nontemporal_load(pr);      // single-use stream: bypass L2
    s8 vr1 = __builtin_nontemporal_load(pr + 1);
    s8 vr2 = __builtin_nontemporal_load(pr + 2);
    s8 vr3 = __builtin_nontemporal_load(pr + 3);
    s8 vi0 = __builtin_nontemporal_load(pi);
    s8 vi1 = __builtin_nontemporal_load(pi + 1);
    s8 vi2 = __builtin_nontemporal_load(pi + 2);
    s8 vi3 = __builtin_nontemporal_load(pi + 3);
    float gr = 0.f, gi = 0.f;
    #pragma unroll
    for (int i = 0; i < 8; i++) {
        float xr, xi;
        xr = bf2f(vr0[i]); xi = bf2f(vi0[i]);
        gr += xr * ur[i] - xi * ui[i];      gi += xr * ui[i] + xi * ur[i];
        xr = bf2f(vr1[i]); xi = bf2f(vi1[i]);
        gr += xr * ur[8+i] - xi * ui[8+i];  gi += xr * ui[8+i] + xi * ur[8+i];
        xr = bf2f(vr2[i]); xi = bf2f(vi2[i]);
        gr += xr * ur[16+i] - xi * ui[16+i]; gi += xr * ui[16+i] + xi * ur[16+i];
        xr = bf2f(vr3[i]); xi = bf2f(vi3[i]);
        gr += xr * ur[24+i] - xi * ui[24+i]; gi += xr * ui[24+i] + xi * ur[24+i];
    }
    gbuf[(x * 2 + 0) * 8192 + rp] = gr;
    gbuf[(x * 2 + 1) * 8192 + rp] = gi;
}

// ---------------- irfft + D-skip + residual: block = rp, scalar gbuf, trig recurrence ----------------
__global__ __launch_bounds__(128) void k_inv(const float* __restrict__ gbuf,
                                             const float* __restrict__ Dp,
                                             const float* __restrict__ xnR,
                                             float* __restrict__ enc,
                                             short* __restrict__ ench,
                                             int wr_enc, int wr_ench) {
    int rp = blockIdx.x;               // uniform -> gbuf loads scalarize
    int d = threadIdx.x;               // 128
    int bc = rp & 255, p = rp >> 8;
    int r = bc * 32 + p;
    const float* gb = gbuf + rp;
    float ang = (float)d * 0.04908738521234052f;   // 2*pi*d/128
    float c1, s1;
    __sincosf(ang, &s1, &c1);
    float cx = c1, sx = s1;
    float acc = gb[0];
    #pragma unroll 4
    for (int x = 1; x < 32; x++) {
        float gr = gb[(2 * x) * 8192];
        float gi = gb[(2 * x + 1) * 8192];
        acc = fmaf(2.f * gr, cx, acc);
        acc = fmaf(-2.f * gi, sx, acc);
        float cn = cx * c1 - sx * s1;
        float sn = sx * c1 + cx * s1;
        cx = cn; sx = sn;
    }
    float ys = acc * (1.f / 128.f);
    float v = ys + Dp[d] * xnR[rp * 128 + d] + enc[r * 128 + d];
    if (wr_enc)  enc[r * 128 + d] = v;
    if (wr_ench) ench[r * 128 + d] = f2bf(v);
}

// ---------------- head via MFMA: out[t][bc] = ow[t][:] . ench[bc][:] ----------------
__global__ __launch_bounds__(256) void k_head(const short* __restrict__ ench,  // [bc][4096]
                                              const short* __restrict__ owh,   // [t][4096]
                                              const float* __restrict__ ob,
                                              const float* __restrict__ stdev,
                                              const float* __restrict__ means,
                                              float* __restrict__ out) {
    int mt = blockIdx.x / 16;
    int nt = blockIdx.x % 16;
    int wave = threadIdx.x >> 6, lane = threadIdx.x & 63;
    int l15 = lane & 15, q = lane >> 4;
    const short* aBase = owh + (mt * 16 + l15) * 4096;
    const short* bBase = ench + (nt * 16 + l15) * 4096;
    f4 acc = {0.f, 0.f, 0.f, 0.f};
    for (int kc = wave * 32; kc < wave * 32 + 32; kc++) {
        s8 a = *(const s8*)(aBase + kc * 32 + q * 8);
        s8 b = *(const s8*)(bBase + kc * 32 + q * 8);
        acc = __builtin_amdgcn_mfma_f32_16x16x32_bf16(a, b, acc, 0, 0, 0);
    }
    __shared__ float red[4][256];
    #pragma unroll
    for (int r = 0; r < 4; r++) red[wave][(q * 4 + r) * 16 + l15] = acc[r];
    __syncthreads();
    int tl = threadIdx.x;
    float v = red[0][tl] + red[1][tl] + red[2][tl] + red[3][tl];
    int tt = mt * 16 + (tl >> 4);
    int bc = nt * 16 + (tl & 15);
    int b = bc >> 5, c = bc & 31;
    out[(b * PREDq + tt) * 32 + c] = (v + ob[tt]) * stdev[bc] + means[bc];
}

extern "C" void kernel_launch(void* const* d_in, const int* in_sizes, int n_in,
                              void* d_out, int out_size, void* d_ws, size_t ws_size,
                              hipStream_t stream) {
    const float* x     = (const float*)d_in[0];
    const float* xproj = (const float*)d_in[4];
    const float* dtw   = (const float*)d_in[5];
    const float* dtb   = (const float*)d_in[6];
    const float* Alog  = (const float*)d_in[7];
    const float* Dp    = (const float*)d_in[8];
    const float* Kr    = (const float*)d_in[9];
    const float* Ki    = (const float*)d_in[10];
    const float* lng   = (const float*)d_in[11];
    const float* lnb   = (const float*)d_in[12];
    const float* ow    = (const float*)d_in[13];
    const float* ob    = (const float*)d_in[14];
    float* out = (float*)d_out;

    float* w = (float*)d_ws;
    float* means  = w; w += 256;
    float* stdev  = w; w += 256;
    short* twA    = (short*)w; w += 4096;
    float* xwT    = w; w += 20480;     // [li][d][80]
    float* dwT    = w; w += 2048;      // [li][r][128]
    float* ktr    = w; w += 65536;     // [li][x][o][i]
    float* kti    = w; w += 65536;
    float* enc    = w; w += 1048576;   // [r][d]
    float* xnR    = w; w += 1048576;   // [rp][d]
    float* deltaT = w; w += 1048576;   // [rp][d]
    float* BmR    = w; w += 262144;    // [rp][s]
    float* CmT    = w; w += 262144;    // [o][rp]
    float* gbuf   = w; w += 524288;    // [x2c][rp]
    float* carry  = w; w += 1048576;   // fp32 [bc][s][d]
    short* ench   = (short*)w; w += 524288;    // bf16 [bc][4096]
    short* owh    = (short*)w; w += 393216;    // bf16 [t][4096]
    short* xfh    = (short*)w; w += 8388608;   // bf16 [m][rp][s]  (16,777,216 shorts)

    k_prep<<<3328, 256, 0, stream>>>(xproj, dtw, Kr, Ki, ow, x,
                                     twA, xwT, dwT, ktr, kti, owh, means, stdev, enc);
    for (int li = 0; li < 2; li++) {
        k_lnproj<<<8192, 128, 0, stream>>>(enc, xwT + li * 10240, dwT + li * 1024,
                                           dtb + li * 128, lng + li * 128, lnb + li * 128,
                                           xnR, deltaT, BmR, CmT);
        k_carry<<<8192, 128, 0, stream>>>(deltaT, xnR, BmR, Alog + li * 4096, carry);
        k_scandft<<<1024, 64, 0, stream>>>(deltaT, xnR, BmR, Alog + li * 4096, twA, carry, xfh);
        k_mix<<<1024, 256, 0, stream>>>(xfh, CmT, ktr + li * 32768, kti + li * 32768, gbuf);
        k_inv<<<8192, 128, 0, stream>>>(gbuf, Dp + li * 128, xnR, enc, ench,
                                        (li == 0) ? 1 : 0, (li == 1) ? 1 : 0);
    }
    k_head<<<192, 256, 0, stream>>>(ench, owh, ob, stdev, means, out);
}

// Round 14
// 322.971 us; speedup vs baseline: 1.1591x; 1.1591x over previous
//
#include <hip/hip_runtime.h>

typedef __attribute__((ext_vector_type(8))) short s8;
typedef __attribute__((ext_vector_type(4))) float f4;

#define PREDq 192

__device__ inline short f2bf(float f) {
    union { float f; unsigned u; } v; v.f = f;
    unsigned r = (v.u + 0x7FFF + ((v.u >> 16) & 1)) >> 16;
    return (short)r;
}
__device__ inline float bf2f(short h) {
    union { unsigned u; float f; } v;
    v.u = ((unsigned)(unsigned short)h) << 16;
    return v.f;
}

// ---------------- fused setup: twiddles + weight transposes + ow->bf16 + stats + embed ----------------
__global__ void k_prep(const float* __restrict__ xw, const float* __restrict__ dw,
                       const float* __restrict__ Kr, const float* __restrict__ Ki,
                       const float* __restrict__ ow, const float* __restrict__ x,
                       short* __restrict__ twA,
                       float* __restrict__ xwT, float* __restrict__ dwT,
                       float* __restrict__ ktr, float* __restrict__ kti,
                       short* __restrict__ owh,
                       float* __restrict__ means, float* __restrict__ stdev,
                       float* __restrict__ enc) {
    if (blockIdx.x >= 3072) {           // ---- stats + embed blocks ----
        int bc = blockIdx.x - 3072;
        int b = bc >> 5, c = bc & 31;
        int t = threadIdx.x;
        __shared__ float xrow[512];
        __shared__ float r1[4], r2[4];
        float s1 = 0.f, s2 = 0.f;
        for (int tt = t; tt < 512; tt += 256) {
            float v = x[(b * 512 + tt) * 32 + c];
            xrow[tt] = v;
            s1 += v; s2 += v * v;
        }
        #pragma unroll
        for (int off = 32; off > 0; off >>= 1) {
            s1 += __shfl_xor(s1, off);
            s2 += __shfl_xor(s2, off);
        }
        int wave = t >> 6, lane = t & 63;
        if (lane == 0) { r1[wave] = s1; r2[wave] = s2; }
        __syncthreads();
        float S1 = r1[0] + r1[1] + r1[2] + r1[3];
        float S2 = r2[0] + r2[1] + r2[2] + r2[3];
        float mu = S1 * (1.f / 512.f);
        float var = S2 * (1.f / 512.f) - mu * mu;
        float sd = sqrtf(var + 1e-5f);
        float inv = 1.f / sd;
        if (t == 0) { means[bc] = mu; stdev[bc] = sd; }
        #pragma unroll
        for (int k = 0; k < 16; k++) {
            int idx = k * 256 + t;                 // < 4096
            int p = idx >> 7, dd = idx & 127;
            int m = dd >> 4, l = dd & 15;
            int tt2 = p * 16 + l;
            float v = 0.f;
            if (tt2 >= 7) v = (xrow[tt2 - 7 + m] - mu) * inv;
            enc[bc * 4096 + idx] = v;              // coalesced
        }
        return;
    }
    int idx = blockIdx.x * 256 + threadIdx.x;
    if (idx < 8192) {                   // twA bf16 [(x*2+c)][d]: c==0 cos, c==1 -sin
        int n = idx >> 7, d = idx & 127;
        int xx = n >> 1, c = n & 1;
        float ang = (float)((xx * d) & 127) * 0.04908738521234052f; // 2*pi/128
        twA[idx] = f2bf((c == 0) ? cosf(ang) : -sinf(ang));
    }
    if (idx < 2 * 128 * 80) {           // xwT[li][d][80]
        int li = idx / 10240, rem = idx % 10240, d = rem / 80, t = rem % 80;
        xwT[idx] = (t < 72) ? xw[li * 9216 + t * 128 + d] : 0.f;
    }
    if (idx < 2 * 8 * 128) {            // dwT[li][r][128]
        int li = idx / 1024, rem = idx % 1024, r = rem / 128, d = rem % 128;
        dwT[idx] = dw[li * 1024 + d * 8 + r];
    }
    if (idx < 2 * 32 * 32 * 32) {       // ktr/kti [li][x][o][i]
        int li = idx >> 15, rem = idx & 32767;
        int xx = rem >> 10, o = (rem >> 5) & 31, i = rem & 31;
        int src = ((li * 32 + i) * 32 + o) * 32 + xx;
        ktr[idx] = Kr[src];
        kti[idx] = Ki[src];
    }
    if (idx < 192 * 4096) {             // owh bf16, native [t][k]
        owh[idx] = f2bf(ow[idx]);
    }
}

// ---------------- LayerNorm + projections (+ aexp precompute in blocks r<32) ----------------
__global__ __launch_bounds__(128) void k_lnproj(const float* __restrict__ enc,
                         const float* __restrict__ xwT,  // [d][80]
                         const float* __restrict__ dwT,  // [r][128]
                         const float* __restrict__ db,   // (128)
                         const float* __restrict__ g, const float* __restrict__ bb,
                         const float* __restrict__ Alog,
                         float* __restrict__ xnR,        // [rp][d]
                         float* __restrict__ deltaT,     // [rp][d]
                         float* __restrict__ BmR,        // [rp][s]
                         float* __restrict__ CmT,        // [o][rp]
                         float* __restrict__ aexp) {     // [s][d]
    int r = blockIdx.x;          // bc*32+p
    int bc = r >> 5, p = r & 31;
    int rp = p * 256 + bc;
    int t = threadIdx.x;         // 128
    if (r < 32) aexp[r * 128 + t] = -__expf(Alog[t * 32 + r]);
    __shared__ float xs[128];
    __shared__ float red[4];
    __shared__ float dr[8];
    float e = enc[r * 128 + t];
    float s1 = e, s2 = e * e;
    #pragma unroll
    for (int off = 32; off > 0; off >>= 1) {
        s1 += __shfl_xor(s1, off);
        s2 += __shfl_xor(s2, off);
    }
    if ((t & 63) == 0) { red[(t >> 6) * 2] = s1; red[(t >> 6) * 2 + 1] = s2; }
    __syncthreads();
    float mu = (red[0] + red[2]) * (1.f / 128.f);
    float var = (red[1] + red[3]) * (1.f / 128.f) - mu * mu;
    float inv = rsqrtf(var + 1e-5f);
    float v = (e - mu) * inv * g[t] + bb[t];
    xs[t] = v;
    xnR[rp * 128 + t] = v;
    __syncthreads();
    if (t < 80) {
        float acc = 0.f;
        const f4* xs4 = (const f4*)xs;
        #pragma unroll 8
        for (int dq = 0; dq < 32; dq++) {
            f4 xv = xs4[dq];
            const float* wp = xwT + dq * 320 + t;
            acc += xv[0] * wp[0] + xv[1] * wp[80] + xv[2] * wp[160] + xv[3] * wp[240];
        }
        if (t < 8) dr[t] = acc;
        else if (t < 40) BmR[rp * 32 + (t - 8)] = acc;
        else if (t < 72) CmT[(t - 40) * 8192 + rp] = acc;
    }
    __syncthreads();
    float a = db[t];
    #pragma unroll
    for (int rr = 0; rr < 8; rr++) a += dr[rr] * dwT[rr * 128 + t];
    float sp = fmaxf(a, 0.f) + log1pf(expf(-fabsf(a)));
    deltaT[rp * 128 + t] = sp;
}

// ---------------- scan carry: exact fp32 scan over p=0..23, checkpoints at 8/16/24 ----------------
__global__ __launch_bounds__(128) void k_carry(const float* __restrict__ deltaT,  // [rp][d]
                                               const float* __restrict__ xnR,     // [rp][d]
                                               const float* __restrict__ BmR,     // [rp][s]
                                               const float* __restrict__ aexp,    // [s][d]
                                               float* __restrict__ carry) {       // [cp][bc][s][d]
    int bc = blockIdx.x >> 5;
    int s  = blockIdx.x & 31;
    int d  = threadIdx.x;
    float A = aexp[s * 128 + d];          // coalesced
    const float* dptr = deltaT + bc * 128 + d;
    const float* xptr = xnR + bc * 128 + d;
    int bvbase = bc * 32 + s;
    int cbase = (bc * 32 + s) * 128 + d;
    float h = 0.f;
    float dl = dptr[0], xv = xptr[0], bv = BmR[bvbase];
    #pragma unroll 4
    for (int p = 0; p < 24; p++) {
        float dln = 0.f, xvn = 0.f, bvn = 0.f;
        if (p < 23) {
            dln = dptr[(p + 1) * 32768];
            xvn = xptr[(p + 1) * 32768];
            bvn = BmR[(p + 1) * 8192 + bvbase];
        }
        h = __expf(dl * A) * h + dl * xv * bv;
        if (p == 7)  carry[cbase] = h;
        if (p == 15) carry[1048576 + cbase] = h;
        if (p == 23) carry[2097152 + cbase] = h;
        dl = dln; xv = xvn; bv = bvn;
    }
}

// ---------------- fused scan + MFMA DFT, wave-autonomous, p-quartered via carry ----------------
// 1 wave per (bc, s-half, p-quarter). lane=(q,l15) holds h for d = kt*32+q*8+j at s=s0+l15
// (MFMA B-fragment layout). All 8 iterations' global loads issued up front.
// xfh layout: [m=(x*2+c)][rp][s]
__global__ __launch_bounds__(64) void k_scandft(const float* __restrict__ deltaT,  // [rp][d]
                                                const float* __restrict__ xnR,     // [rp][d]
                                                const float* __restrict__ BmR,     // [rp][s]
                                                const float* __restrict__ aexp,    // [s][d]
                                                const short* __restrict__ twA,
                                                const float* __restrict__ carry,   // [cp][bc][s][d]
                                                short* __restrict__ xfh) {
    int bc = blockIdx.x >> 3;
    int s0 = ((blockIdx.x >> 2) & 1) * 16;
    int pq = blockIdx.x & 3;
    int p0 = pq * 8;
    int lane = threadIdx.x;
    int l15 = lane & 15, q = lane >> 4;
    int s = s0 + l15;

    __shared__ float dlb[8][128];
    __shared__ float xvb[8][128];

    // ---- all 8 iterations' global loads up front (misses overlap) ----
    const float2* dp2 = (const float2*)deltaT;
    const float2* xp2 = (const float2*)xnR;
    int rbase = bc * 64 + lane;            // float2 index of row element
    int bvbase = bc * 32 + s;
    float2 dl2[8], xv2[8];
    float bv[8];
    #pragma unroll
    for (int pi = 0; pi < 8; pi++) {
        int p = p0 + pi;
        dl2[pi] = dp2[p * 16384 + rbase];
        xv2[pi] = xp2[p * 16384 + rbase];
        bv[pi]  = BmR[p * 8192 + bvbase];
    }

    // twiddle A-fragments: 4 m-tiles x 4 kt (one-time)
    s8 afr[4][4];
    #pragma unroll
    for (int mt = 0; mt < 4; mt++)
        #pragma unroll
        for (int kt = 0; kt < 4; kt++)
            afr[mt][kt] = *(const s8*)(twA + (mt * 16 + l15) * 128 + kt * 32 + q * 8);

    // decay constants via precomputed aexp (quad-broadcast f4)
    float A[4][8], h[4][8];
    const f4* ab = (const f4*)(aexp + s * 128);
    #pragma unroll
    for (int kt = 0; kt < 4; kt++) {
        f4 a0 = ab[kt * 8 + q * 2];
        f4 a1 = ab[kt * 8 + q * 2 + 1];
        #pragma unroll
        for (int j = 0; j < 4; j++) { A[kt][j] = a0[j]; A[kt][4 + j] = a1[j]; }
    }
    if (pq > 0) {      // resume from checkpoint (quad-broadcast f4 loads, once)
        const f4* cb = (const f4*)(carry + (pq - 1) * 1048576 + (bc * 32 + s) * 128);
        #pragma unroll
        for (int kt = 0; kt < 4; kt++) {
            f4 c0 = cb[kt * 8 + q * 2];
            f4 c1 = cb[kt * 8 + q * 2 + 1];
            #pragma unroll
            for (int j = 0; j < 4; j++) { h[kt][j] = c0[j]; h[kt][4 + j] = c1[j]; }
        }
    } else {
        #pragma unroll
        for (int kt = 0; kt < 4; kt++)
            #pragma unroll
            for (int j = 0; j < 8; j++) h[kt][j] = 0.f;
    }

    // stage all 8 iterations into LDS (wave-local, no barrier needed)
    #pragma unroll
    for (int pi = 0; pi < 8; pi++) {
        ((float2*)&dlb[pi][0])[lane] = dl2[pi];
        ((float2*)&xvb[pi][0])[lane] = xv2[pi];
    }

    for (int pi = 0; pi < 8; pi++) {
        int p = p0 + pi;
        float bvc = bv[pi];
        // scan update + pack B fragments from registers
        s8 bfr[4];
        #pragma unroll
        for (int kt = 0; kt < 4; kt++) {
            f4 dl0 = *(const f4*)(&dlb[pi][kt * 32 + q * 8]);      // quad-broadcast b128
            f4 dl1 = *(const f4*)(&dlb[pi][kt * 32 + q * 8 + 4]);
            f4 xv0 = *(const f4*)(&xvb[pi][kt * 32 + q * 8]);
            f4 xv1 = *(const f4*)(&xvb[pi][kt * 32 + q * 8 + 4]);
            #pragma unroll
            for (int j = 0; j < 4; j++) {
                float dl = dl0[j], xv = xv0[j];
                h[kt][j] = __expf(dl * A[kt][j]) * h[kt][j] + dl * xv * bvc;
            }
            #pragma unroll
            for (int j = 0; j < 4; j++) {
                float dl = dl1[j], xv = xv1[j];
                h[kt][4 + j] = __expf(dl * A[kt][4 + j]) * h[kt][4 + j] + dl * xv * bvc;
            }
            union { int i[4]; s8 v; } u;
            #pragma unroll
            for (int t2 = 0; t2 < 4; t2++) {
                int lo = __float_as_int(h[kt][2 * t2]);
                int hi = __float_as_int(h[kt][2 * t2 + 1]);
                u.i[t2] = __builtin_amdgcn_perm(hi, lo, 0x07060302);  // [hi.hi16 | lo.hi16]
            }
            bfr[kt] = u.v;
        }
        // MFMA: 4 m-tiles of 16 modes
        f4 acc0 = {0.f, 0.f, 0.f, 0.f}, acc1 = acc0, acc2 = acc0, acc3 = acc0;
        #pragma unroll
        for (int kt = 0; kt < 4; kt++) {
            acc0 = __builtin_amdgcn_mfma_f32_16x16x32_bf16(afr[0][kt], bfr[kt], acc0, 0, 0, 0);
            acc1 = __builtin_amdgcn_mfma_f32_16x16x32_bf16(afr[1][kt], bfr[kt], acc1, 0, 0, 0);
            acc2 = __builtin_amdgcn_mfma_f32_16x16x32_bf16(afr[2][kt], bfr[kt], acc2, 0, 0, 0);
            acc3 = __builtin_amdgcn_mfma_f32_16x16x32_bf16(afr[3][kt], bfr[kt], acc3, 0, 0, 0);
        }
        // D[row=q*4+r][col=l15] -> m = mt*16 + q*4 + r
        int rp = p * 256 + bc;
        long ob = (long)rp * 32 + s;
        #pragma unroll
        for (int r = 0; r < 4; r++) {
            int m = q * 4 + r;
            xfh[(m +  0) * 262144 + ob] = (short)(__float_as_int(acc0[r]) >> 16);
            xfh[(m + 16) * 262144 + ob] = (short)(__float_as_int(acc1[r]) >> 16);
            xfh[(m + 32) * 262144 + ob] = (short)(__float_as_int(acc2[r]) >> 16);
            xfh[(m + 48) * 262144 + ob] = (short)(__float_as_int(acc3[r]) >> 16);
        }
    }
}

// ---------------- mode mixing: u = K·Cm (SGPR weights), g = <xf, u> ----------------
__global__ __launch_bounds__(256) void k_mix(const short* __restrict__ xfh,  // [m][rp][s]
                                             const float* __restrict__ CmT,  // [o][rp]
                                             const float* __restrict__ ktr,  // [x][o][i]
                                             const float* __restrict__ kti,
                                             float* __restrict__ gbuf) {     // [x2c][rp]
    int x = blockIdx.x >> 5;
    int rp = (blockIdx.x & 31) * 256 + threadIdx.x;
    const float* kr = ktr + x * 1024;   // wave-uniform -> s_load bursts
    const float* ki = kti + x * 1024;
    float ur[32], ui[32];
    #pragma unroll
    for (int i = 0; i < 32; i++) { ur[i] = 0.f; ui[i] = 0.f; }
    for (int o = 0; o < 32; o++) {
        float co = CmT[o * 8192 + rp];
        const float* kro = kr + o * 32;
        const float* kio = ki + o * 32;
        #pragma unroll
        for (int i = 0; i < 32; i++) {
            ur[i] = fmaf(co, kro[i], ur[i]);
            ui[i] = fmaf(co, kio[i], ui[i]);
        }
    }
    const s8* pr = (const s8*)(xfh + (x * 2 + 0) * 262144 + rp * 32);  // 64B/lane contiguous
    const s8* pi = (const s8*)(xfh + (x * 2 + 1) * 262144 + rp * 32);
    s8 vr0 = pr[0], vr1 = pr[1], vr2 = pr[2], vr3 = pr[3];
    s8 vi0 = pi[0], vi1 = pi[1], vi2 = pi[2], vi3 = pi[3];
    float gr = 0.f, gi = 0.f;
    #pragma unroll
    for (int i = 0; i < 8; i++) {
        float xr, xi;
        xr = bf2f(vr0[i]); xi = bf2f(vi0[i]);
        gr += xr * ur[i] - xi * ui[i];      gi += xr * ui[i] + xi * ur[i];
        xr = bf2f(vr1[i]); xi = bf2f(vi1[i]);
        gr += xr * ur[8+i] - xi * ui[8+i];  gi += xr * ui[8+i] + xi * ur[8+i];
        xr = bf2f(vr2[i]); xi = bf2f(vi2[i]);
        gr += xr * ur[16+i] - xi * ui[16+i]; gi += xr * ui[16+i] + xi * ur[16+i];
        xr = bf2f(vr3[i]); xi = bf2f(vi3[i]);
        gr += xr * ur[24+i] - xi * ui[24+i]; gi += xr * ui[24+i] + xi * ur[24+i];
    }
    gbuf[(x * 2 + 0) * 8192 + rp] = gr;
    gbuf[(x * 2 + 1) * 8192 + rp] = gi;
}

// ---------------- irfft + D-skip + residual: block = rp, scalar gbuf, trig recurrence ----------------
__global__ __launch_bounds__(128) void k_inv(const float* __restrict__ gbuf,
                                             const float* __restrict__ Dp,
                                             const float* __restrict__ xnR,
                                             float* __restrict__ enc,
                                             short* __restrict__ ench,
                                             int wr_enc, int wr_ench) {
    int rp = blockIdx.x;               // uniform -> gbuf loads scalarize
    int d = threadIdx.x;               // 128
    int bc = rp & 255, p = rp >> 8;
    int r = bc * 32 + p;
    const float* gb = gbuf + rp;
    float ang = (float)d * 0.04908738521234052f;   // 2*pi*d/128
    float c1, s1;
    __sincosf(ang, &s1, &c1);
    float cx = c1, sx = s1;
    float acc = gb[0];
    #pragma unroll 4
    for (int x = 1; x < 32; x++) {
        float gr = gb[(2 * x) * 8192];
        float gi = gb[(2 * x + 1) * 8192];
        acc = fmaf(2.f * gr, cx, acc);
        acc = fmaf(-2.f * gi, sx, acc);
        float cn = cx * c1 - sx * s1;
        float sn = sx * c1 + cx * s1;
        cx = cn; sx = sn;
    }
    float ys = acc * (1.f / 128.f);
    float v = ys + Dp[d] * xnR[rp * 128 + d] + enc[r * 128 + d];
    if (wr_enc)  enc[r * 128 + d] = v;
    if (wr_ench) ench[r * 128 + d] = f2bf(v);
}

// ---------------- head via MFMA: out[t][bc] = ow[t][:] . ench[bc][:] ----------------
__global__ __launch_bounds__(256) void k_head(const short* __restrict__ ench,  // [bc][4096]
                                              const short* __restrict__ owh,   // [t][4096]
                                              const float* __restrict__ ob,
                                              const float* __restrict__ stdev,
                                              const float* __restrict__ means,
                                              float* __restrict__ out) {
    int mt = blockIdx.x / 16;
    int nt = blockIdx.x % 16;
    int wave = threadIdx.x >> 6, lane = threadIdx.x & 63;
    int l15 = lane & 15, q = lane >> 4;
    const short* aBase = owh + (mt * 16 + l15) * 4096;
    const short* bBase = ench + (nt * 16 + l15) * 4096;
    f4 acc = {0.f, 0.f, 0.f, 0.f};
    for (int kc = wave * 32; kc < wave * 32 + 32; kc++) {
        s8 a = *(const s8*)(aBase + kc * 32 + q * 8);
        s8 b = *(const s8*)(bBase + kc * 32 + q * 8);
        acc = __builtin_amdgcn_mfma_f32_16x16x32_bf16(a, b, acc, 0, 0, 0);
    }
    __shared__ float red[4][256];
    #pragma unroll
    for (int r = 0; r < 4; r++) red[wave][(q * 4 + r) * 16 + l15] = acc[r];
    __syncthreads();
    int tl = threadIdx.x;
    float v = red[0][tl] + red[1][tl] + red[2][tl] + red[3][tl];
    int tt = mt * 16 + (tl >> 4);
    int bc = nt * 16 + (tl & 15);
    int b = bc >> 5, c = bc & 31;
    out[(b * PREDq + tt) * 32 + c] = (v + ob[tt]) * stdev[bc] + means[bc];
}

extern "C" void kernel_launch(void* const* d_in, const int* in_sizes, int n_in,
                              void* d_out, int out_size, void* d_ws, size_t ws_size,
                              hipStream_t stream) {
    const float* x     = (const float*)d_in[0];
    const float* xproj = (const float*)d_in[4];
    const float* dtw   = (const float*)d_in[5];
    const float* dtb   = (const float*)d_in[6];
    const float* Alog  = (const float*)d_in[7];
    const float* Dp    = (const float*)d_in[8];
    const float* Kr    = (const float*)d_in[9];
    const float* Ki    = (const float*)d_in[10];
    const float* lng   = (const float*)d_in[11];
    const float* lnb   = (const float*)d_in[12];
    const float* ow    = (const float*)d_in[13];
    const float* ob    = (const float*)d_in[14];
    float* out = (float*)d_out;

    float* w = (float*)d_ws;
    float* means  = w; w += 256;
    float* stdev  = w; w += 256;
    short* twA    = (short*)w; w += 4096;
    float* xwT    = w; w += 20480;     // [li][d][80]
    float* dwT    = w; w += 2048;      // [li][r][128]
    float* ktr    = w; w += 65536;     // [li][x][o][i]
    float* kti    = w; w += 65536;
    float* aexp   = w; w += 4096;      // [s][d]
    float* enc    = w; w += 1048576;   // [r][d]
    float* xnR    = w; w += 1048576;   // [rp][d]
    float* deltaT = w; w += 1048576;   // [rp][d]
    float* BmR    = w; w += 262144;    // [rp][s]
    float* CmT    = w; w += 262144;    // [o][rp]
    float* gbuf   = w; w += 524288;    // [x2c][rp]
    float* carry  = w; w += 3145728;   // fp32 [cp=3][bc][s][d]
    short* ench   = (short*)w; w += 524288;    // bf16 [bc][4096]
    short* owh    = (short*)w; w += 393216;    // bf16 [t][4096]
    short* xfh    = (short*)w; w += 8388608;   // bf16 [m][rp][s]  (16,777,216 shorts)

    k_prep<<<3328, 256, 0, stream>>>(xproj, dtw, Kr, Ki, ow, x,
                                     twA, xwT, dwT, ktr, kti, owh, means, stdev, enc);
    for (int li = 0; li < 2; li++) {
        k_lnproj<<<8192, 128, 0, stream>>>(enc, xwT + li * 10240, dwT + li * 1024,
                                           dtb + li * 128, lng + li * 128, lnb + li * 128,
                                           Alog + li * 4096,
                                           xnR, deltaT, BmR, CmT, aexp);
        k_carry<<<8192, 128, 0, stream>>>(deltaT, xnR, BmR, aexp, carry);
        k_scandft<<<2048, 64, 0, stream>>>(deltaT, xnR, BmR, aexp, twA, carry, xfh);
        k_mix<<<1024, 256, 0, stream>>>(xfh, CmT, ktr + li * 32768, kti + li * 32768, gbuf);
        k_inv<<<8192, 128, 0, stream>>>(gbuf, Dp + li * 128, xnR, enc, ench,
                                        (li == 0) ? 1 : 0, (li == 1) ? 1 : 0);
    }
    k_head<<<192, 256, 0, stream>>>(ench, owh, ob, stdev, means, out);
}